// Round 16
// baseline (42.845 us; speedup 1.0000x reference)
//
#include <hip/hip_runtime.h>

#define B_      2
#define NCH     4
#define DIMX    18
#define NPT     (18*18*18)        /* 5832 */
#define TIL     183               /* j-tiles of 32 */
#define ITIL    184               /* i-tiles incl pad */
#define NPTP    (ITIL*32)         /* 5888 */
#define IBLOCKS 46                /* 4 i-tiles per block (1 per wave) */
#define JSP     11                /* j splits: 46*11*2 = 1012 blocks ~ single resident round */
#define NB      (IBLOCKS*JSP*B_)  /* 1012 */
#define FSC     (1.2011224087864498f / 5.0f)   /* sqrt(log2 e)/5 */
#define QPAD    -30000.0f

typedef __attribute__((ext_vector_type(8)))  short short8;
typedef __attribute__((ext_vector_type(4)))  short short4_;
typedef __attribute__((ext_vector_type(16))) float f32x16;
typedef __attribute__((ext_vector_type(4)))  int   int4_;

#define EXP2(x) __builtin_amdgcn_exp2f(x)
#define MFMA32(a, b, c) __builtin_amdgcn_mfma_f32_32x32x16_bf16(a, b, c, 0, 0, 0)

__device__ __forceinline__ unsigned short bf16rtn(float f) {
  unsigned u = __float_as_uint(f);
  u += 0x7fffu + ((u >> 16) & 1u);
  return (unsigned short)(u >> 16);
}
__device__ __forceinline__ float bf2f(unsigned short s) {
  return __uint_as_float(((unsigned)s) << 16);
}

__device__ __forceinline__ float blockReduceSum(float v) {
  #pragma unroll
  for (int o = 32; o > 0; o >>= 1) v += __shfl_down(v, o, 64);
  __shared__ float red[4];
  int wid = threadIdx.x >> 6, lane = threadIdx.x & 63;
  if (lane == 0) red[wid] = v;
  __syncthreads();
  v = (threadIdx.x < 4) ? red[threadIdx.x] : 0.0f;
  if (wid == 0) {
    v += __shfl_down(v, 2, 64);
    v += __shfl_down(v, 1, 64);
  }
  return v;  // valid on thread 0
}

// ---------------- prep ----------------
__global__ void prep_kernel(const float* __restrict__ I, const float* __restrict__ U,
                            short8* __restrict__ AHI, short8* __restrict__ BHL,
                            float4* __restrict__ H) {
  const short8 zer = {0, 0, 0, 0, 0, 0, 0, 0};
  int idx = blockIdx.x * 256 + threadIdx.x;
  if (idx >= B_ * NPTP) return;
  int bb = idx / NPTP, n = idx - bb * NPTP;
  short8 ahi, bhi, blo;
  float4 hh;
  if (n < NPT) {
    int x = n / (DIMX * DIMX);
    int rem = n - x * DIMX * DIMX;
    int y = rem / DIMX, z = rem - y * DIMX;
    float f0 = x * FSC, f1 = y * FSC, f2 = z * FSC;
    float f3 = I[(size_t)(bb * 3 + 0) * NPT + n] * FSC;
    float f4 = I[(size_t)(bb * 3 + 1) * NPT + n] * FSC;
    float f5 = I[(size_t)(bb * 3 + 2) * NPT + n] * FSC;
    float q = -0.5f * (f0*f0 + f1*f1 + f2*f2 + f3*f3 + f4*f4 + f5*f5);
    float av[8] = {f0, f1, f2, f3, f4, f5, q, 1.0f};
    float bv[8] = {f0, f1, f2, f3, f4, f5, 1.0f, q};
    #pragma unroll
    for (int e = 0; e < 8; ++e) {
      ahi[e] = (short)bf16rtn(av[e]);
      unsigned short bh = bf16rtn(bv[e]);
      bhi[e] = (short)bh;
      blo[e] = (short)bf16rtn(bv[e] - bf2f(bh));
    }
    float u0 = U[(size_t)(bb * NCH + 0) * NPT + n];
    float u1 = U[(size_t)(bb * NCH + 1) * NPT + n];
    float u2 = U[(size_t)(bb * NCH + 2) * NPT + n];
    float u3 = U[(size_t)(bb * NCH + 3) * NPT + n];
    float m = fmaxf(fmaxf(u0, u1), fmaxf(u2, u3));
    float e0 = __expf(u0-m), e1 = __expf(u1-m), e2 = __expf(u2-m), e3 = __expf(u3-m);
    float inv = 1.0f / (e0 + e1 + e2 + e3);
    hh = make_float4(e0*inv, e1*inv, e2*inv, e3*inv);
  } else {
    ahi = zer; bhi = zer; blo = zer;
    bhi[7] = (short)bf16rtn(QPAD);   // pad j row -> w = 0 for real i
    hh = make_float4(0.f, 0.f, 0.f, 0.f);
  }
  AHI[idx] = ahi;
  BHL[(size_t)idx * 2]     = bhi;
  BHL[(size_t)idx * 2 + 1] = blo;
  H[idx] = hh;
}

__device__ __forceinline__ float expsum16(const f32x16 acc) {
  float e[16];
  #pragma unroll
  for (int r = 0; r < 16; ++r) e[r] = EXP2(acc[r]);
  float s8[8];
  #pragma unroll
  for (int r = 0; r < 8; ++r) s8[r] = e[2*r] + e[2*r+1];
  float s4[4];
  #pragma unroll
  for (int r = 0; r < 4; ++r) s4[r] = s8[2*r] + s8[2*r+1];
  return (s4[0] + s4[1]) + (s4[2] + s4[3]);
}

// ---------------- pass1: ONE i-tile per wave, 8 waves/SIMD ----------------
__global__ void __launch_bounds__(256, 8) pass1_kernel(const short8* __restrict__ AHI,
                                                       const short8* __restrict__ BHL,
                                                       float* __restrict__ part) {
  const short8 zer = {0, 0, 0, 0, 0, 0, 0, 0};
  int tid = threadIdx.x, wid = tid >> 6, l = tid & 63, h = l >> 5, li = l & 31;
  int bb = blockIdx.z, jc = blockIdx.y;
  int i0 = (blockIdx.x * 4 + wid) * 32 + li;
  size_t pbase = (size_t)bb * NPTP;
  int t0 = jc * TIL / JSP, t1 = (jc + 1) * TIL / JSP;

  short8 b1_0 = AHI[pbase + i0];

  f32x16 z;
  #pragma unroll
  for (int r = 0; r < 16; ++r) z[r] = 0.0f;

  float sacc0 = 0.0f;
  short8 a_cur = BHL[(pbase + (size_t)t0 * 32 + li) * 2 + h];
  for (int t = t0; t < t1; ++t) {
    short8 a_nxt = (t + 1 < t1) ? BHL[(pbase + (size_t)(t+1) * 32 + li) * 2 + h] : zer;
    f32x16 acc0 = MFMA32(a_cur, b1_0, z);
    sacc0 += expsum16(acc0);
    a_cur = a_nxt;
  }
  sacc0 += __shfl_xor(sacc0, 32, 64);
  if (h == 0) part[((size_t)bb * JSP + jc) * NPTP + i0] = sacc0;
}

// ---------------- finalize ----------------
__global__ void finalize_kernel(const float4* __restrict__ H, const float* __restrict__ part,
                                unsigned short* __restrict__ Vt, float4* __restrict__ G4) {
  int idx = blockIdx.x * 256 + threadIdx.x;
  if (idx >= B_ * NPTP) return;
  int bb = idx / NPTP, ii = idx - bb * NPTP;
  if (ii < NPT) {
    float s = 0.0f;
    #pragma unroll
    for (int k = 0; k < JSP; ++k) s += part[((size_t)bb * JSP + k) * NPTP + ii];
    float nrm = rsqrtf(s + 1e-20f);
    float4 hh = H[idx];
    Vt[((size_t)bb * 4 + 0) * NPTP + ii] = bf16rtn(hh.x * nrm);
    Vt[((size_t)bb * 4 + 1) * NPTP + ii] = bf16rtn(hh.y * nrm);
    Vt[((size_t)bb * 4 + 2) * NPTP + ii] = bf16rtn(hh.z * nrm);
    Vt[((size_t)bb * 4 + 3) * NPTP + ii] = bf16rtn(hh.w * nrm);
    G4[idx] = make_float4((1.0f - hh.x) * nrm, (1.0f - hh.y) * nrm,
                          (1.0f - hh.z) * nrm, (1.0f - hh.w) * nrm);
  } else {
    Vt[((size_t)bb * 4 + 0) * NPTP + ii] = 0;
    Vt[((size_t)bb * 4 + 1) * NPTP + ii] = 0;
    Vt[((size_t)bb * 4 + 2) * NPTP + ii] = 0;
    Vt[((size_t)bb * 4 + 3) * NPTP + ii] = 0;
    G4[idx] = make_float4(0.f, 0.f, 0.f, 0.f);
  }
}

__device__ __forceinline__ void ldv(const unsigned short* __restrict__ vrow, int j32,
                                    int h, bool cok, short8* vf1, short8* vf2) {
  const short4_ zer4 = {0, 0, 0, 0};
  short4_ va = cok ? *(const short4_*)(vrow + j32 + 4*h)      : zer4;
  short4_ vb = cok ? *(const short4_*)(vrow + j32 + 8 + 4*h)  : zer4;
  short4_ vc = cok ? *(const short4_*)(vrow + j32 + 16 + 4*h) : zer4;
  short4_ vd = cok ? *(const short4_*)(vrow + j32 + 24 + 4*h) : zer4;
  short8 f1, f2;
  #pragma unroll
  for (int e = 0; e < 4; ++e) {
    f1[e] = va[e]; f1[4 + e] = vb[e];
    f2[e] = vc[e]; f2[4 + e] = vd[e];
  }
  *vf1 = f1; *vf2 = f2;
}

// ---------------- pass2: ONE i-tile per wave, 4 waves/SIMD ----------------
__global__ void __launch_bounds__(256, 4) pass2_kernel(const short8* __restrict__ AHI,
                                                       const short8* __restrict__ BHL,
                                                       const unsigned short* __restrict__ Vt,
                                                       const float4* __restrict__ G4,
                                                       float* __restrict__ pl) {
  const short8 zer = {0, 0, 0, 0, 0, 0, 0, 0};
  int tid = threadIdx.x, wid = tid >> 6, l = tid & 63, h = l >> 5, li = l & 31;
  int bb = blockIdx.z, jc = blockIdx.y;
  int i0 = (blockIdx.x * 4 + wid) * 32 + li;
  size_t pbase = (size_t)bb * NPTP;
  int t0 = jc * TIL / JSP, t1 = (jc + 1) * TIL / JSP;

  short8 b1_0 = AHI[pbase + i0];
  float4 g0 = G4[pbase + i0];
  bool cok = li < 4;
  const unsigned short* vrow = Vt + ((size_t)bb * 4 + (cok ? li : 0)) * NPTP;

  f32x16 z;
  #pragma unroll
  for (int r = 0; r < 16; ++r) z[r] = 0.0f;
  f32x16 d2_0 = z;

  short8 a_cur = BHL[(pbase + (size_t)t0 * 32 + li) * 2 + h];
  short8 vf1c, vf2c;
  ldv(vrow, t0 * 32, h, cok, &vf1c, &vf2c);

  for (int t = t0; t < t1; ++t) {
    short8 a_nxt = zer, vf1n = zer, vf2n = zer;
    if (t + 1 < t1) {
      a_nxt = BHL[(pbase + (size_t)(t+1) * 32 + li) * 2 + h];
      ldv(vrow, (t + 1) * 32, h, cok, &vf1n, &vf2n);
    }
    f32x16 acc0 = MFMA32(a_cur, b1_0, z);

    float w0[16];
    #pragma unroll
    for (int r = 0; r < 16; ++r) w0[r] = EXP2(acc0[r]);
    int p0[8];
    #pragma unroll
    for (int r = 0; r < 8; ++r)
      asm("v_cvt_pk_bf16_f32 %0, %1, %2" : "=v"(p0[r]) : "v"(w0[2*r]), "v"(w0[2*r+1]));
    union { int4_ iv; short8 sv; } u1a, u2a;
    u1a.iv = (int4_){p0[0], p0[1], p0[2], p0[3]};
    u2a.iv = (int4_){p0[4], p0[5], p0[6], p0[7]};

    d2_0 = MFMA32(vf1c, u1a.sv, d2_0);
    d2_0 = MFMA32(vf2c, u2a.sv, d2_0);

    a_cur = a_nxt; vf1c = vf1n; vf2c = vf2n;
  }

  float loss = d2_0[0] * g0.x + d2_0[1] * g0.y + d2_0[2] * g0.z + d2_0[3] * g0.w;
  float r = blockReduceSum(loss);
  if (tid == 0) pl[((size_t)bb * JSP + jc) * IBLOCKS + blockIdx.x] = r;
}

__global__ void reduce_kernel(const float* __restrict__ pl, int n, float* __restrict__ out) {
  float v = 0.0f;
  for (int k = threadIdx.x; k < n; k += 256) v += pl[k];
  float r = blockReduceSum(v);
  if (threadIdx.x == 0) out[0] = r;
}

extern "C" void kernel_launch(void* const* d_in, const int* in_sizes, int n_in,
                              void* d_out, int out_size, void* d_ws, size_t ws_size,
                              hipStream_t stream) {
  const float* I = (const float*)d_in[0];
  const float* U = (const float*)d_in[1];
  float* out = (float*)d_out;

  char* w = (char*)d_ws;
  short8* AHI = (short8*)w;                 w += (size_t)B_ * NPTP * 16;
  short8* BHL = (short8*)w;                 w += (size_t)B_ * NPTP * 32;
  float4* H   = (float4*)w;                 w += (size_t)B_ * NPTP * 16;
  float*  part = (float*)w;                 w += (size_t)B_ * JSP * NPTP * 4;
  unsigned short* Vt = (unsigned short*)w;  w += (size_t)B_ * 4 * NPTP * 2;
  float4* G4  = (float4*)w;                 w += (size_t)B_ * NPTP * 16;
  float*  pl  = (float*)w;                  w += (size_t)NB * 4;

  prep_kernel<<<(B_ * NPTP + 255) / 256, 256, 0, stream>>>(I, U, AHI, BHL, H);
  dim3 grid(IBLOCKS, JSP, B_);
  pass1_kernel<<<grid, 256, 0, stream>>>(AHI, BHL, part);
  finalize_kernel<<<(B_ * NPTP + 255) / 256, 256, 0, stream>>>(H, part, Vt, G4);
  pass2_kernel<<<grid, 256, 0, stream>>>(AHI, BHL, Vt, G4, pl);
  reduce_kernel<<<1, 256, 0, stream>>>(pl, NB, out);
}

// Round 17
// 41.044 us; speedup vs baseline: 1.0439x; 1.0439x over previous
//
#include <hip/hip_runtime.h>

#define B_      2
#define NCH     4
#define DIMX    18
#define NPT     (18*18*18)        /* 5832 */
#define TIL     183               /* j-tiles of 32 */
#define ITIL    184               /* i-tiles incl pad */
#define NPTP    (ITIL*32)         /* 5888 */
#define IBLOCKS 46                /* 4 i-tiles per block (1 per wave) */
#define JSP     16                /* j splits: 46*16*2 = 1472 blocks */
#define NB      (IBLOCKS*JSP*B_)  /* 1472 */
#define FSC     (1.2011224087864498f / 5.0f)   /* sqrt(log2 e)/5 */
#define QPAD    -30000.0f

typedef __attribute__((ext_vector_type(8)))  short short8;
typedef __attribute__((ext_vector_type(4)))  short short4_;
typedef __attribute__((ext_vector_type(16))) float f32x16;
typedef __attribute__((ext_vector_type(4)))  int   int4_;

#define EXP2(x) __builtin_amdgcn_exp2f(x)
#define MFMA32(a, b, c) __builtin_amdgcn_mfma_f32_32x32x16_bf16(a, b, c, 0, 0, 0)

__device__ __forceinline__ unsigned short bf16rtn(float f) {
  unsigned u = __float_as_uint(f);
  u += 0x7fffu + ((u >> 16) & 1u);
  return (unsigned short)(u >> 16);
}
__device__ __forceinline__ float bf2f(unsigned short s) {
  return __uint_as_float(((unsigned)s) << 16);
}

__device__ __forceinline__ float blockReduceSum(float v) {
  #pragma unroll
  for (int o = 32; o > 0; o >>= 1) v += __shfl_down(v, o, 64);
  __shared__ float red[4];
  int wid = threadIdx.x >> 6, lane = threadIdx.x & 63;
  if (lane == 0) red[wid] = v;
  __syncthreads();
  v = (threadIdx.x < 4) ? red[threadIdx.x] : 0.0f;
  if (wid == 0) {
    v += __shfl_down(v, 2, 64);
    v += __shfl_down(v, 1, 64);
  }
  return v;  // valid on thread 0
}

// ---------------- prep ----------------
__global__ void prep_kernel(const float* __restrict__ I, const float* __restrict__ U,
                            short8* __restrict__ AHI, short8* __restrict__ BHL,
                            float4* __restrict__ H) {
  const short8 zer = {0, 0, 0, 0, 0, 0, 0, 0};
  int idx = blockIdx.x * 256 + threadIdx.x;
  if (idx >= B_ * NPTP) return;
  int bb = idx / NPTP, n = idx - bb * NPTP;
  short8 ahi, bhi, blo;
  float4 hh;
  if (n < NPT) {
    int x = n / (DIMX * DIMX);
    int rem = n - x * DIMX * DIMX;
    int y = rem / DIMX, z = rem - y * DIMX;
    float f0 = x * FSC, f1 = y * FSC, f2 = z * FSC;
    float f3 = I[(size_t)(bb * 3 + 0) * NPT + n] * FSC;
    float f4 = I[(size_t)(bb * 3 + 1) * NPT + n] * FSC;
    float f5 = I[(size_t)(bb * 3 + 2) * NPT + n] * FSC;
    float q = -0.5f * (f0*f0 + f1*f1 + f2*f2 + f3*f3 + f4*f4 + f5*f5);
    float av[8] = {f0, f1, f2, f3, f4, f5, q, 1.0f};
    float bv[8] = {f0, f1, f2, f3, f4, f5, 1.0f, q};
    #pragma unroll
    for (int e = 0; e < 8; ++e) {
      ahi[e] = (short)bf16rtn(av[e]);
      unsigned short bh = bf16rtn(bv[e]);
      bhi[e] = (short)bh;
      blo[e] = (short)bf16rtn(bv[e] - bf2f(bh));
    }
    float u0 = U[(size_t)(bb * NCH + 0) * NPT + n];
    float u1 = U[(size_t)(bb * NCH + 1) * NPT + n];
    float u2 = U[(size_t)(bb * NCH + 2) * NPT + n];
    float u3 = U[(size_t)(bb * NCH + 3) * NPT + n];
    float m = fmaxf(fmaxf(u0, u1), fmaxf(u2, u3));
    float e0 = __expf(u0-m), e1 = __expf(u1-m), e2 = __expf(u2-m), e3 = __expf(u3-m);
    float inv = 1.0f / (e0 + e1 + e2 + e3);
    hh = make_float4(e0*inv, e1*inv, e2*inv, e3*inv);
  } else {
    ahi = zer; bhi = zer; blo = zer;
    bhi[7] = (short)bf16rtn(QPAD);   // pad j row -> w = 0 for real i
    hh = make_float4(0.f, 0.f, 0.f, 0.f);
  }
  AHI[idx] = ahi;
  BHL[(size_t)idx * 2]     = bhi;
  BHL[(size_t)idx * 2 + 1] = blo;
  H[idx] = hh;
}

__device__ __forceinline__ float expsum16(const f32x16 acc) {
  float e[16];
  #pragma unroll
  for (int r = 0; r < 16; ++r) e[r] = EXP2(acc[r]);
  float s8[8];
  #pragma unroll
  for (int r = 0; r < 8; ++r) s8[r] = e[2*r] + e[2*r+1];
  float s4[4];
  #pragma unroll
  for (int r = 0; r < 4; ++r) s4[r] = s8[2*r] + s8[2*r+1];
  return (s4[0] + s4[1]) + (s4[2] + s4[3]);
}

// ---------------- pass1: ONE i-tile per wave, high occupancy ----------------
__global__ void __launch_bounds__(256, 4) pass1_kernel(const short8* __restrict__ AHI,
                                                       const short8* __restrict__ BHL,
                                                       float* __restrict__ part) {
  const short8 zer = {0, 0, 0, 0, 0, 0, 0, 0};
  int tid = threadIdx.x, wid = tid >> 6, l = tid & 63, h = l >> 5, li = l & 31;
  int bb = blockIdx.z, jc = blockIdx.y;
  int i0 = (blockIdx.x * 4 + wid) * 32 + li;
  size_t pbase = (size_t)bb * NPTP;
  int t0 = jc * TIL / JSP, t1 = (jc + 1) * TIL / JSP;

  short8 b1_0 = AHI[pbase + i0];

  f32x16 z;
  #pragma unroll
  for (int r = 0; r < 16; ++r) z[r] = 0.0f;

  float sacc0 = 0.0f;
  short8 a_cur = BHL[(pbase + (size_t)t0 * 32 + li) * 2 + h];
  for (int t = t0; t < t1; ++t) {
    short8 a_nxt = (t + 1 < t1) ? BHL[(pbase + (size_t)(t+1) * 32 + li) * 2 + h] : zer;
    f32x16 acc0 = MFMA32(a_cur, b1_0, z);
    sacc0 += expsum16(acc0);
    a_cur = a_nxt;
  }
  sacc0 += __shfl_xor(sacc0, 32, 64);
  if (h == 0) part[((size_t)bb * JSP + jc) * NPTP + i0] = sacc0;
}

// ---------------- finalize ----------------
__global__ void finalize_kernel(const float4* __restrict__ H, const float* __restrict__ part,
                                unsigned short* __restrict__ Vt, float4* __restrict__ G4) {
  int idx = blockIdx.x * 256 + threadIdx.x;
  if (idx >= B_ * NPTP) return;
  int bb = idx / NPTP, ii = idx - bb * NPTP;
  if (ii < NPT) {
    float s = 0.0f;
    #pragma unroll
    for (int k = 0; k < JSP; ++k) s += part[((size_t)bb * JSP + k) * NPTP + ii];
    float nrm = rsqrtf(s + 1e-20f);
    float4 hh = H[idx];
    Vt[((size_t)bb * 4 + 0) * NPTP + ii] = bf16rtn(hh.x * nrm);
    Vt[((size_t)bb * 4 + 1) * NPTP + ii] = bf16rtn(hh.y * nrm);
    Vt[((size_t)bb * 4 + 2) * NPTP + ii] = bf16rtn(hh.z * nrm);
    Vt[((size_t)bb * 4 + 3) * NPTP + ii] = bf16rtn(hh.w * nrm);
    G4[idx] = make_float4((1.0f - hh.x) * nrm, (1.0f - hh.y) * nrm,
                          (1.0f - hh.z) * nrm, (1.0f - hh.w) * nrm);
  } else {
    Vt[((size_t)bb * 4 + 0) * NPTP + ii] = 0;
    Vt[((size_t)bb * 4 + 1) * NPTP + ii] = 0;
    Vt[((size_t)bb * 4 + 2) * NPTP + ii] = 0;
    Vt[((size_t)bb * 4 + 3) * NPTP + ii] = 0;
    G4[idx] = make_float4(0.f, 0.f, 0.f, 0.f);
  }
}

__device__ __forceinline__ void ldv(const unsigned short* __restrict__ vrow, int j32,
                                    int h, bool cok, short8* vf1, short8* vf2) {
  const short4_ zer4 = {0, 0, 0, 0};
  short4_ va = cok ? *(const short4_*)(vrow + j32 + 4*h)      : zer4;
  short4_ vb = cok ? *(const short4_*)(vrow + j32 + 8 + 4*h)  : zer4;
  short4_ vc = cok ? *(const short4_*)(vrow + j32 + 16 + 4*h) : zer4;
  short4_ vd = cok ? *(const short4_*)(vrow + j32 + 24 + 4*h) : zer4;
  short8 f1, f2;
  #pragma unroll
  for (int e = 0; e < 4; ++e) {
    f1[e] = va[e]; f1[4 + e] = vb[e];
    f2[e] = vc[e]; f2[4 + e] = vd[e];
  }
  *vf1 = f1; *vf2 = f2;
}

// ---------------- pass2: ONE i-tile per wave, high occupancy ----------------
__global__ void __launch_bounds__(256, 4) pass2_kernel(const short8* __restrict__ AHI,
                                                       const short8* __restrict__ BHL,
                                                       const unsigned short* __restrict__ Vt,
                                                       const float4* __restrict__ G4,
                                                       float* __restrict__ pl) {
  const short8 zer = {0, 0, 0, 0, 0, 0, 0, 0};
  int tid = threadIdx.x, wid = tid >> 6, l = tid & 63, h = l >> 5, li = l & 31;
  int bb = blockIdx.z, jc = blockIdx.y;
  int i0 = (blockIdx.x * 4 + wid) * 32 + li;
  size_t pbase = (size_t)bb * NPTP;
  int t0 = jc * TIL / JSP, t1 = (jc + 1) * TIL / JSP;

  short8 b1_0 = AHI[pbase + i0];
  float4 g0 = G4[pbase + i0];
  bool cok = li < 4;
  const unsigned short* vrow = Vt + ((size_t)bb * 4 + (cok ? li : 0)) * NPTP;

  f32x16 z;
  #pragma unroll
  for (int r = 0; r < 16; ++r) z[r] = 0.0f;
  f32x16 d2_0 = z;

  short8 a_cur = BHL[(pbase + (size_t)t0 * 32 + li) * 2 + h];
  short8 vf1c, vf2c;
  ldv(vrow, t0 * 32, h, cok, &vf1c, &vf2c);

  for (int t = t0; t < t1; ++t) {
    short8 a_nxt = zer, vf1n = zer, vf2n = zer;
    if (t + 1 < t1) {
      a_nxt = BHL[(pbase + (size_t)(t+1) * 32 + li) * 2 + h];
      ldv(vrow, (t + 1) * 32, h, cok, &vf1n, &vf2n);
    }
    f32x16 acc0 = MFMA32(a_cur, b1_0, z);

    float w0[16];
    #pragma unroll
    for (int r = 0; r < 16; ++r) w0[r] = EXP2(acc0[r]);
    int p0[8];
    #pragma unroll
    for (int r = 0; r < 8; ++r)
      asm("v_cvt_pk_bf16_f32 %0, %1, %2" : "=v"(p0[r]) : "v"(w0[2*r]), "v"(w0[2*r+1]));
    union { int4_ iv; short8 sv; } u1a, u2a;
    u1a.iv = (int4_){p0[0], p0[1], p0[2], p0[3]};
    u2a.iv = (int4_){p0[4], p0[5], p0[6], p0[7]};

    d2_0 = MFMA32(vf1c, u1a.sv, d2_0);
    d2_0 = MFMA32(vf2c, u2a.sv, d2_0);

    a_cur = a_nxt; vf1c = vf1n; vf2c = vf2n;
  }

  float loss = d2_0[0] * g0.x + d2_0[1] * g0.y + d2_0[2] * g0.z + d2_0[3] * g0.w;
  float r = blockReduceSum(loss);
  if (tid == 0) pl[((size_t)bb * JSP + jc) * IBLOCKS + blockIdx.x] = r;
}

__global__ void reduce_kernel(const float* __restrict__ pl, int n, float* __restrict__ out) {
  float v = 0.0f;
  for (int k = threadIdx.x; k < n; k += 256) v += pl[k];
  float r = blockReduceSum(v);
  if (threadIdx.x == 0) out[0] = r;
}

extern "C" void kernel_launch(void* const* d_in, const int* in_sizes, int n_in,
                              void* d_out, int out_size, void* d_ws, size_t ws_size,
                              hipStream_t stream) {
  const float* I = (const float*)d_in[0];
  const float* U = (const float*)d_in[1];
  float* out = (float*)d_out;

  char* w = (char*)d_ws;
  short8* AHI = (short8*)w;                 w += (size_t)B_ * NPTP * 16;
  short8* BHL = (short8*)w;                 w += (size_t)B_ * NPTP * 32;
  float4* H   = (float4*)w;                 w += (size_t)B_ * NPTP * 16;
  float*  part = (float*)w;                 w += (size_t)B_ * JSP * NPTP * 4;
  unsigned short* Vt = (unsigned short*)w;  w += (size_t)B_ * 4 * NPTP * 2;
  float4* G4  = (float4*)w;                 w += (size_t)B_ * NPTP * 16;
  float*  pl  = (float*)w;                  w += (size_t)NB * 4;

  prep_kernel<<<(B_ * NPTP + 255) / 256, 256, 0, stream>>>(I, U, AHI, BHL, H);
  dim3 grid(IBLOCKS, JSP, B_);
  pass1_kernel<<<grid, 256, 0, stream>>>(AHI, BHL, part);
  finalize_kernel<<<(B_ * NPTP + 255) / 256, 256, 0, stream>>>(H, part, Vt, G4);
  pass2_kernel<<<grid, 256, 0, stream>>>(AHI, BHL, Vt, G4, pl);
  reduce_kernel<<<1, 256, 0, stream>>>(pl, NB, out);
}